// Round 6
// baseline (439.418 us; speedup 1.0000x reference)
//
#include <hip/hip_runtime.h>
#include <cstdint>
#include <cstddef>

// Problem dims
#define NB   16384   // batch tokens
#define DD   256     // model dim
#define DIN  257     // D+1 (x ++ t)
#define KP1  288     // DIN padded to mult of 32
#define HH   1024    // hidden
#define NE   8       // experts
#define GMAX 33792   // 264*128: 2*NB rows + per-expert pad to 128
#define GMT  264     // GMAX/128 row tiles

// ctrl layout (ints), atomics padded to separate 64B lines:
//   counts[e] at ctrl[e*16]; cursor[e] at ctrl[128+e*16]; offp[e] at ctrl[256+e] (offp[8]=total)
#define CTRL_INTS 272

typedef unsigned short u16;
typedef __bf16 bf16x8 __attribute__((ext_vector_type(8)));
typedef float  f32x4  __attribute__((ext_vector_type(4)));
typedef unsigned short u16x4 __attribute__((ext_vector_type(4)));

__device__ __forceinline__ u16 f2bf(float f) {
  union { float f; unsigned u; } v; v.f = f;
  return (u16)((v.u + 0x7FFFu + ((v.u >> 16) & 1u)) >> 16);  // RNE
}
__device__ __forceinline__ float bf2f(u16 h) {
  union { unsigned u; float f; } v; v.u = ((unsigned)h) << 16;
  return v.f;
}

#define GLDS16(g, l) __builtin_amdgcn_global_load_lds( \
    (const __attribute__((address_space(1))) void*)(g), \
    (__attribute__((address_space(3))) void*)(l), 16, 0, 0)

// LDS k-quad swizzle: quad q of tile-row r lives at slot r*4 + (q ^ ((r>>1)&3)).
// Write side stays lane-contiguous (global_load_lds constraint); read side gets
// distinct bank-sets within each 8-lane phase of ds_read_b128 (kills the 4x conflict).
__device__ __forceinline__ int swz_u16(int row, int q) {
  return row * 32 + ((q ^ ((row >> 1) & 3)) * 8);
}

// ---------------- xt = [x, t, 0-pad] as 3 bf16 planes, vectorized x4 ----------------
__global__ void build_xt3(const float* __restrict__ x, const float* __restrict__ t,
                          u16* __restrict__ xh, u16* __restrict__ xm, u16* __restrict__ xl) {
  long i = (long)blockIdx.x * 256 + threadIdx.x;   // grid exact: NB*72/256
  int b = (int)(i / 72), qd = (int)(i % 72);       // 72 quads of 4 = KP1
  f32x4 v;
  if (qd < 64)       v = *(const f32x4*)&x[(long)b * DD + qd * 4];
  else if (qd == 64) v = (f32x4){t[b], 0.f, 0.f, 0.f};
  else               v = (f32x4){0.f, 0.f, 0.f, 0.f};
  u16x4 h, m, l;
  #pragma unroll
  for (int j = 0; j < 4; ++j) {
    u16 hi = f2bf(v[j]);  float r1 = v[j] - bf2f(hi);
    u16 mi = f2bf(r1);    float r2 = r1 - bf2f(mi);
    h[j] = hi; m[j] = mi; l[j] = f2bf(r2);
  }
  long o = (long)b * KP1 + qd * 4;
  *(u16x4*)&xh[o] = h;  *(u16x4*)&xm[o] = m;  *(u16x4*)&xl[o] = l;
}

// ------ transpose-convert W[K][N] f32 -> Wt[N][Kpad] bf16 (hi, optional mid/lo) ------
__global__ void transpose_w(const float* __restrict__ W, u16* __restrict__ Wh,
                            u16* __restrict__ Wm, u16* __restrict__ Wl,
                            int Kdim, int Ndim, int Kpad, long sW, long sWt) {
  __shared__ float tile[32][33];
  int e = blockIdx.z;
  int k0 = blockIdx.x * 32, n0 = blockIdx.y * 32;
  int tx = threadIdx.x, ty = threadIdx.y;       // (32,8)
  const float* Wb = W + (long)e * sW;
  #pragma unroll
  for (int i = 0; i < 4; ++i) {
    int k = k0 + ty + i * 8;
    tile[ty + i * 8][tx] = (k < Kdim) ? Wb[(long)k * Ndim + (n0 + tx)] : 0.f;
  }
  __syncthreads();
  #pragma unroll
  for (int i = 0; i < 4; ++i) {
    int n = n0 + ty + i * 8;
    float v = tile[tx][ty + i * 8];
    long o = (long)e * sWt + (long)n * Kpad + k0 + tx;
    u16 hi = f2bf(v);
    Wh[o] = hi;
    if (Wm) {
      float r1 = v - bf2f(hi);
      u16 mi = f2bf(r1);
      Wm[o] = mi;
      Wl[o] = f2bf(r1 - bf2f(mi));
    }
  }
}

// ------- Router GEMM, 3-plane bf16 emulated f32, FUSED logits partials -------
__global__ __launch_bounds__(256, 2)
void router_gemm_emul3(const u16* __restrict__ Ah, const u16* __restrict__ Am, const u16* __restrict__ Al,
                       const u16* __restrict__ Bh, const u16* __restrict__ Bm, const u16* __restrict__ Bl,
                       const float* __restrict__ bias, const float* __restrict__ Rw2,
                       float* __restrict__ pbuf) {
  __shared__ __align__(16) u16 S[6][128 * 32];   // 0..2 = A planes, 3..5 = B planes
  int tid = threadIdx.x;
  int m0 = blockIdx.y * 128, n0 = blockIdx.x * 128;
  const u16* Ap[3] = {Ah, Am, Al};
  const u16* Bp[3] = {Bh, Bm, Bl};
  const u16 *ag[3][2], *bg[3][2];
  u16 *la[3][2], *lb[3][2];
  #pragma unroll
  for (int r = 0; r < 2; ++r) {
    int i = r * 256 + tid;
    int row = i >> 2;
    int qa = (i & 3) ^ ((row >> 1) & 3);        // swizzled quad for this slot
    int kq = qa * 8;
    #pragma unroll
    for (int p = 0; p < 3; ++p) {
      ag[p][r] = Ap[p] + (long)(m0 + row) * KP1 + kq;
      bg[p][r] = Bp[p] + (long)(n0 + row) * KP1 + kq;
      la[p][r] = &S[p][i * 8];
      lb[p][r] = &S[3 + p][i * 8];
    }
  }
  int lane = tid & 63, wv = tid >> 6;
  int wm = wv >> 1, wn = wv & 1;
  int q = lane >> 4, c = lane & 15;
  int offA[4], offB[4];
  #pragma unroll
  for (int t4 = 0; t4 < 4; ++t4) {
    offA[t4] = swz_u16(wm * 64 + t4 * 16 + c, q);
    offB[t4] = swz_u16(wn * 64 + t4 * 16 + c, q);
  }
  f32x4 acc[4][4];
  #pragma unroll
  for (int mi = 0; mi < 4; ++mi)
    #pragma unroll
    for (int ni = 0; ni < 4; ++ni) acc[mi][ni] = (f32x4){0.f, 0.f, 0.f, 0.f};

  for (int k0 = 0; k0 < KP1; k0 += 32) {
    __syncthreads();
    #pragma unroll
    for (int r = 0; r < 2; ++r)
      #pragma unroll
      for (int p = 0; p < 3; ++p) {
        GLDS16(ag[p][r] + k0, la[p][r]);
        GLDS16(bg[p][r] + k0, lb[p][r]);
      }
    __syncthreads();
    bf16x8 av[3][4], bv[3][4];
    #pragma unroll
    for (int mi = 0; mi < 4; ++mi)
      #pragma unroll
      for (int p = 0; p < 3; ++p) av[p][mi] = *(const bf16x8*)&S[p][offA[mi]];
    #pragma unroll
    for (int ni = 0; ni < 4; ++ni)
      #pragma unroll
      for (int p = 0; p < 3; ++p) bv[p][ni] = *(const bf16x8*)&S[3 + p][offB[ni]];
    #pragma unroll
    for (int mi = 0; mi < 4; ++mi)
      #pragma unroll
      for (int ni = 0; ni < 4; ++ni) {
        acc[mi][ni] = __builtin_amdgcn_mfma_f32_16x16x32_bf16(av[0][mi], bv[0][ni], acc[mi][ni], 0, 0, 0);
        acc[mi][ni] = __builtin_amdgcn_mfma_f32_16x16x32_bf16(av[0][mi], bv[1][ni], acc[mi][ni], 0, 0, 0);
        acc[mi][ni] = __builtin_amdgcn_mfma_f32_16x16x32_bf16(av[1][mi], bv[0][ni], acc[mi][ni], 0, 0, 0);
        acc[mi][ni] = __builtin_amdgcn_mfma_f32_16x16x32_bf16(av[0][mi], bv[2][ni], acc[mi][ni], 0, 0, 0);
        acc[mi][ni] = __builtin_amdgcn_mfma_f32_16x16x32_bf16(av[2][mi], bv[0][ni], acc[mi][ni], 0, 0, 0);
      }
  }
  // ---- fused epilogue: partial logits for this 64-col half ----
  float rw2f[4][8];
  #pragma unroll
  for (int ni = 0; ni < 4; ++ni) {
    const float* p = Rw2 + (long)(n0 + wn * 64 + ni * 16 + c) * NE;
    f32x4 a = *(const f32x4*)p, b2 = *(const f32x4*)(p + 4);
    #pragma unroll
    for (int j = 0; j < 4; ++j) { rw2f[ni][j] = a[j]; rw2f[ni][4 + j] = b2[j]; }
  }
  float bi[4];
  #pragma unroll
  for (int ni = 0; ni < 4; ++ni) bi[ni] = bias[n0 + wn * 64 + ni * 16 + c];
  #pragma unroll
  for (int mi = 0; mi < 4; ++mi)
    #pragma unroll
    for (int r = 0; r < 4; ++r) {
      int token = m0 + wm * 64 + mi * 16 + q * 4 + r;
      float part[8] = {0.f, 0.f, 0.f, 0.f, 0.f, 0.f, 0.f, 0.f};
      #pragma unroll
      for (int ni = 0; ni < 4; ++ni) {
        float v = acc[mi][ni][r] + bi[ni];
        v = v / (1.f + expf(-v));               // high-precision silu
        #pragma unroll
        for (int e = 0; e < 8; ++e) part[e] += v * rw2f[ni][e];
      }
      #pragma unroll
      for (int m = 1; m < 16; m <<= 1)          // butterfly over c (lane&15)
        #pragma unroll
        for (int e = 0; e < 8; ++e) part[e] += __shfl_xor(part[e], m, 64);
      if (c == 0) {
        float* dst = pbuf + ((long)(blockIdx.x * 2 + wn) * NB + token) * 8;
        *(f32x4*)dst       = (f32x4){part[0], part[1], part[2], part[3]};
        *(f32x4*)(dst + 4) = (f32x4){part[4], part[5], part[6], part[7]};
      }
    }
}

// ---- reduce 16 half-plane partials -> logits -> top-2 -> softmax -> counts ----
__global__ void reduce_topk(const float* __restrict__ pbuf, const float* __restrict__ Rb2,
                            int* __restrict__ tk_idx, float* __restrict__ tk_alpha,
                            int* __restrict__ ctrl) {
  __shared__ int lh[NE];
  int tid = threadIdx.x;
  if (tid < NE) lh[tid] = 0;
  __syncthreads();
  int token = blockIdx.x * 256 + tid;             // grid = NB/256
  float v[8];
  #pragma unroll
  for (int e = 0; e < 8; ++e) v[e] = Rb2[e];
  #pragma unroll
  for (int p = 0; p < 16; ++p) {
    const float* src = pbuf + ((long)p * NB + token) * 8;
    f32x4 a = *(const f32x4*)src, b = *(const f32x4*)(src + 4);
    #pragma unroll
    for (int j = 0; j < 4; ++j) { v[j] += a[j]; v[4 + j] += b[j]; }
  }
  int i0 = 0;
  #pragma unroll
  for (int e = 1; e < NE; ++e) if (v[e] > v[i0]) i0 = e;     // strict: lowest idx on tie
  int i1 = -1;
  #pragma unroll
  for (int e = 0; e < NE; ++e) { if (e == i0) continue; if (i1 < 0 || v[e] > v[i1]) i1 = e; }
  float d  = v[i1] - v[i0];
  float e1 = expf(d);
  float a0 = 1.f / (1.f + e1);
  float a1 = e1 / (1.f + e1);
  tk_idx[token * 2]     = i0;  tk_idx[token * 2 + 1]   = i1;
  tk_alpha[token * 2]   = a0;  tk_alpha[token * 2 + 1] = a1;
  atomicAdd(&lh[i0], 1);  atomicAdd(&lh[i1], 1);
  __syncthreads();
  if (tid < NE) atomicAdd(&ctrl[tid * 16], lh[tid]);   // counts, 64B-padded lines
}

__global__ void compute_offsets(int* __restrict__ ctrl) {
  if (threadIdx.x == 0 && blockIdx.x == 0) {
    int total = 0;
    for (int e = 0; e < NE; ++e) {
      ctrl[256 + e] = total;
      total += (ctrl[e * 16] + 127) & ~127;       // pad each expert segment to 128 rows
    }
    ctrl[256 + NE] = total;
  }
}

// ------- block-aggregated rowmap: LDS rank + ONE global atomic per (expert,block) -------
__global__ void build_rowmap(const int* __restrict__ tk_idx, int* __restrict__ ctrl,
                             int* __restrict__ grow, int* __restrict__ tok2slot) {
  __shared__ int lh[NE];
  __shared__ int gb[NE];
  int tid = threadIdx.x;
  if (tid < NE) lh[tid] = 0;
  __syncthreads();
  int token = blockIdx.x * 256 + tid;             // grid = NB/256
  int e0 = tk_idx[token * 2], e1 = tk_idx[token * 2 + 1];
  int l0 = atomicAdd(&lh[e0], 1);
  int l1 = atomicAdd(&lh[e1], 1);
  __syncthreads();
  if (tid < NE) gb[tid] = atomicAdd(&ctrl[128 + tid * 16], lh[tid]);  // cursor, padded
  __syncthreads();
  int g0 = ctrl[256 + e0] + gb[e0] + l0;
  int g1 = ctrl[256 + e1] + gb[e1] + l1;
  grow[g0] = token;  grow[g1] = token;
  tok2slot[token * 2] = g0;  tok2slot[token * 2 + 1] = g1;
}

// ---------------- Grouped expert GEMM: 128x128 tile, BK = 32*NKT, swizzled LDS ----------------
template<int NKT, bool GATHER, bool SILU, bool OUTF32>
__global__ __launch_bounds__(256, 2)
void gemm_grouped(const u16* __restrict__ A, int lda,
                  const u16* __restrict__ Wt, long wstride, int ldw,
                  const float* __restrict__ bias, int bstride,
                  u16* __restrict__ C, int ldc,
                  float* __restrict__ Out, int ldo,
                  const int* __restrict__ offp,
                  const int* __restrict__ grow,
                  int K) {
  int m0 = blockIdx.y * 128, n0 = blockIdx.x * 128;
  if (m0 >= offp[NE]) return;                     // block-uniform early out
  int e = 0;
  while (m0 >= offp[e + 1]) ++e;
  __shared__ __align__(16) u16 As[NKT][128 * 32];
  __shared__ __align__(16) u16 Bs[NKT][128 * 32];
  int tid = threadIdx.x;
  const u16 *ag[NKT][2], *bg[NKT][2];
  u16 *la[NKT][2], *lb[NKT][2];
  #pragma unroll
  for (int s = 0; s < NKT; ++s)
    #pragma unroll
    for (int r = 0; r < 2; ++r) {
      int i = r * 256 + tid;
      int row = i >> 2;
      int qa = (i & 3) ^ ((row >> 1) & 3);        // swizzled quad for this slot
      int kq = qa * 8 + s * 32;
      long arow = m0 + row;
      if (GATHER) arow = grow[arow];
      ag[s][r] = A + arow * lda + kq;
      bg[s][r] = Wt + (long)e * wstride + (long)(n0 + row) * ldw + kq;
      la[s][r] = &As[s][i * 8];
      lb[s][r] = &Bs[s][i * 8];
    }
  int lane = tid & 63, wv = tid >> 6;
  int wm = wv >> 1, wn = wv & 1;
  int q = lane >> 4, c = lane & 15;
  int offA[4], offB[4];
  #pragma unroll
  for (int t4 = 0; t4 < 4; ++t4) {
    offA[t4] = swz_u16(wm * 64 + t4 * 16 + c, q);
    offB[t4] = swz_u16(wn * 64 + t4 * 16 + c, q);
  }
  f32x4 acc[4][4];
  #pragma unroll
  for (int mi = 0; mi < 4; ++mi)
    #pragma unroll
    for (int ni = 0; ni < 4; ++ni) acc[mi][ni] = (f32x4){0.f, 0.f, 0.f, 0.f};

  for (int k0 = 0; k0 < K; k0 += 32 * NKT) {
    __syncthreads();
    #pragma unroll
    for (int s = 0; s < NKT; ++s)
      #pragma unroll
      for (int r = 0; r < 2; ++r) {
        GLDS16(ag[s][r] + k0, la[s][r]);
        GLDS16(bg[s][r] + k0, lb[s][r]);
      }
    __syncthreads();
    #pragma unroll
    for (int s = 0; s < NKT; ++s) {
      bf16x8 av[4], bv[4];
      #pragma unroll
      for (int mi = 0; mi < 4; ++mi)
        av[mi] = *(const bf16x8*)&As[s][offA[mi]];
      #pragma unroll
      for (int ni = 0; ni < 4; ++ni)
        bv[ni] = *(const bf16x8*)&Bs[s][offB[ni]];
      #pragma unroll
      for (int mi = 0; mi < 4; ++mi)
        #pragma unroll
        for (int ni = 0; ni < 4; ++ni)
          acc[mi][ni] = __builtin_amdgcn_mfma_f32_16x16x32_bf16(av[mi], bv[ni], acc[mi][ni], 0, 0, 0);
    }
  }
  #pragma unroll
  for (int mi = 0; mi < 4; ++mi)
    #pragma unroll
    for (int r = 0; r < 4; ++r) {
      int row = wm * 64 + mi * 16 + q * 4 + r;
      #pragma unroll
      for (int ni = 0; ni < 4; ++ni) {
        int col = n0 + wn * 64 + ni * 16 + c;
        float v = acc[mi][ni][r] + bias[e * bstride + col];
        if constexpr (SILU) v = v / (1.f + __expf(-v));
        if constexpr (OUTF32) {
          Out[(long)(m0 + row) * ldo + col] = v;
        } else {
          C[(long)(m0 + row) * ldc + col] = f2bf(v);
        }
      }
    }
}

// ---------------- combine: out[token] = a0*eo[slot0] + a1*eo[slot1] ----------------
__global__ void combine_out(const float* __restrict__ eo, const int* __restrict__ tok2slot,
                            const float* __restrict__ tk_alpha, float* __restrict__ out) {
  int i = blockIdx.x * 256 + threadIdx.x;         // grid exact: NB*DD/4/256
  int token = i >> 6, c4 = (i & 63) * 4;
  long s0 = tok2slot[token * 2], s1 = tok2slot[token * 2 + 1];
  float a0 = tk_alpha[token * 2], a1 = tk_alpha[token * 2 + 1];
  f32x4 v0 = *(const f32x4*)&eo[s0 * DD + c4];
  f32x4 v1 = *(const f32x4*)&eo[s1 * DD + c4];
  f32x4 r;
  #pragma unroll
  for (int j = 0; j < 4; ++j) r[j] = a0 * v0[j] + a1 * v1[j];
  *(f32x4*)&out[(long)token * DD + c4] = r;
}

extern "C" void kernel_launch(void* const* d_in, const int* in_sizes, int n_in,
                              void* d_out, int out_size, void* d_ws, size_t ws_size,
                              hipStream_t stream) {
  const float* t   = (const float*)d_in[0];
  const float* x   = (const float*)d_in[1];
  const float* Rw1 = (const float*)d_in[2];
  const float* Rb1 = (const float*)d_in[3];
  const float* Rw2 = (const float*)d_in[4];
  const float* Rb2 = (const float*)d_in[5];
  const float* Ew1 = (const float*)d_in[6];
  const float* Eb1 = (const float*)d_in[7];
  const float* Ew2 = (const float*)d_in[8];
  const float* Eb2 = (const float*)d_in[9];
  const float* Ew3 = (const float*)d_in[10];
  const float* Eb3 = (const float*)d_in[11];
  float* out = (float*)d_out;                     // reference output dtype is float32

  char* w = (char*)d_ws;
  size_t off = 0;
  auto alloc = [&](size_t bytes) { char* p = w + off; off = (off + bytes + 255) & ~(size_t)255; return p; };
  int*   ctrl     = (int*)  alloc(CTRL_INTS * 4);
  int*   grow     = (int*)  alloc((size_t)GMAX * 4);
  size_t zero_end = off;                                       // ctrl + grow need zeroing
  int*   tok2slot = (int*)  alloc((size_t)NB * 2 * 4);
  int*   tk_idx   = (int*)  alloc((size_t)NB * 2 * 4);
  float* tk_alpha = (float*)alloc((size_t)NB * 2 * 4);
  float* pbuf     = (float*)alloc((size_t)16 * NB * 8 * 4);    // 16 half-plane logits partials
  u16* xh  = (u16*)alloc((size_t)NB * KP1 * 2);
  u16* xm  = (u16*)alloc((size_t)NB * KP1 * 2);
  u16* xl  = (u16*)alloc((size_t)NB * KP1 * 2);
  u16* R1h = (u16*)alloc((size_t)HH * KP1 * 2);
  u16* R1m = (u16*)alloc((size_t)HH * KP1 * 2);
  u16* R1l = (u16*)alloc((size_t)HH * KP1 * 2);
  u16* E1t = (u16*)alloc((size_t)NE * HH * KP1 * 2);
  u16* E2t = (u16*)alloc((size_t)NE * HH * HH * 2);
  u16* E3t = (u16*)alloc((size_t)NE * DD * HH * 2);
  u16* H1  = (u16*)alloc((size_t)GMAX * HH * 2);
  u16* H2  = (u16*)alloc((size_t)GMAX * HH * 2);
  float* eo = (float*)H1;    // GMAX*DD*4 = 35MB <= 69MB; written by G3 after G2 consumed H1

  hipMemsetAsync(d_ws, 0, zero_end, stream);       // counts/cursor/offp + grow (pad rows -> token 0)

  build_xt3<<<(NB * 72) / 256, 256, 0, stream>>>(x, t, xh, xm, xl);
  dim3 tb(32, 8);
  transpose_w<<<dim3(KP1 / 32, HH / 32, 1),  tb, 0, stream>>>(Rw1, R1h, R1m, R1l, DIN, HH, KP1, 0, 0);
  transpose_w<<<dim3(KP1 / 32, HH / 32, NE), tb, 0, stream>>>(Ew1, E1t, nullptr, nullptr, DIN, HH, KP1, (long)DIN * HH, (long)HH * KP1);
  transpose_w<<<dim3(HH / 32, HH / 32, NE),  tb, 0, stream>>>(Ew2, E2t, nullptr, nullptr, HH, HH, HH, (long)HH * HH, (long)HH * HH);
  transpose_w<<<dim3(HH / 32, DD / 32, NE),  tb, 0, stream>>>(Ew3, E3t, nullptr, nullptr, HH, DD, HH, (long)HH * DD, (long)DD * HH);

  router_gemm_emul3<<<dim3(HH / 128, NB / 128), 256, 0, stream>>>(xh, xm, xl, R1h, R1m, R1l, Rb1, Rw2, pbuf);
  reduce_topk<<<NB / 256, 256, 0, stream>>>(pbuf, Rb2, tk_idx, tk_alpha, ctrl);
  compute_offsets<<<1, 64, 0, stream>>>(ctrl);
  build_rowmap<<<NB / 256, 256, 0, stream>>>(tk_idx, ctrl, grow, tok2slot);

  const int* offp = ctrl + 256;
  // G1: H1 = silu(gather(xt_hi) @ Ew1^T + Eb1)   (K=288 -> NKT=3, BK=96, 3 iters)
  gemm_grouped<3, true, true, false><<<dim3(HH / 128, GMT), 256, 0, stream>>>(
      xh, KP1, E1t, (long)HH * KP1, KP1, Eb1, HH, H1, HH, nullptr, 0, offp, grow, KP1);
  // G2: H2 = silu(H1 @ Ew2^T + Eb2)              (K=1024 -> NKT=2, BK=64)
  gemm_grouped<2, false, true, false><<<dim3(HH / 128, GMT), 256, 0, stream>>>(
      H1, HH, E2t, (long)HH * HH, HH, Eb2, HH, H2, HH, nullptr, 0, offp, nullptr, HH);
  // G3: eo[slot] = H2 @ Ew3^T + Eb3              (K=1024 -> NKT=2)
  gemm_grouped<2, false, false, true><<<dim3(DD / 128, GMT), 256, 0, stream>>>(
      H2, HH, E3t, (long)DD * HH, HH, Eb3, DD, nullptr, 0, eo, DD, offp, nullptr, HH);
  // out[token] = a0*eo[s0] + a1*eo[s1]
  combine_out<<<(NB * DD / 4) / 256, 256, 0, stream>>>(eo, tok2slot, tk_alpha, out);
}

// Round 7
// 407.734 us; speedup vs baseline: 1.0777x; 1.0777x over previous
//
#include <hip/hip_runtime.h>
#include <cstdint>
#include <cstddef>

// Problem dims
#define NB   16384   // batch tokens
#define DD   256     // model dim
#define DIN  257     // D+1 (x ++ t)
#define KP1  288     // DIN padded to mult of 32
#define HH   1024    // hidden
#define NE   8       // experts
#define GMAX 33792   // 264*128: 2*NB rows + per-expert pad to 128
#define GMT  264     // GMAX/128 row tiles (divisible by 8)

// ctrl layout (ints), atomics padded to separate 64B lines:
//   counts[e] at ctrl[e*16]; cursor[e] at ctrl[128+e*16]; offp[e] at ctrl[256+e] (offp[8]=total)
#define CTRL_INTS 272

typedef unsigned short u16;
typedef __bf16 bf16x8 __attribute__((ext_vector_type(8)));
typedef float  f32x4  __attribute__((ext_vector_type(4)));
typedef unsigned short u16x4 __attribute__((ext_vector_type(4)));

__device__ __forceinline__ u16 f2bf(float f) {
  union { float f; unsigned u; } v; v.f = f;
  return (u16)((v.u + 0x7FFFu + ((v.u >> 16) & 1u)) >> 16);  // RNE
}
__device__ __forceinline__ float bf2f(u16 h) {
  union { unsigned u; float f; } v; v.u = ((unsigned)h) << 16;
  return v.f;
}

#define GLDS16(g, l) __builtin_amdgcn_global_load_lds( \
    (const __attribute__((address_space(1))) void*)(g), \
    (__attribute__((address_space(3))) void*)(l), 16, 0, 0)

// LDS k-quad swizzle: quad q of tile-row r lives at slot r*4 + (q ^ ((r>>1)&3)).
// Write side stays lane-contiguous (global_load_lds constraint); read side gets
// distinct bank-sets within each 8-lane phase of ds_read_b128 (conflicts: 8.5M -> 0).
__device__ __forceinline__ int swz_u16(int row, int q) {
  return row * 32 + ((q ^ ((row >> 1) & 3)) * 8);
}

// ---------------- xt = [x, t, 0-pad] as 3 bf16 planes, vectorized x4 ----------------
__global__ void build_xt3(const float* __restrict__ x, const float* __restrict__ t,
                          u16* __restrict__ xh, u16* __restrict__ xm, u16* __restrict__ xl) {
  long i = (long)blockIdx.x * 256 + threadIdx.x;   // grid exact: NB*72/256
  int b = (int)(i / 72), qd = (int)(i % 72);       // 72 quads of 4 = KP1
  f32x4 v;
  if (qd < 64)       v = *(const f32x4*)&x[(long)b * DD + qd * 4];
  else if (qd == 64) v = (f32x4){t[b], 0.f, 0.f, 0.f};
  else               v = (f32x4){0.f, 0.f, 0.f, 0.f};
  u16x4 h, m, l;
  #pragma unroll
  for (int j = 0; j < 4; ++j) {
    u16 hi = f2bf(v[j]);  float r1 = v[j] - bf2f(hi);
    u16 mi = f2bf(r1);    float r2 = r1 - bf2f(mi);
    h[j] = hi; m[j] = mi; l[j] = f2bf(r2);
  }
  long o = (long)b * KP1 + qd * 4;
  *(u16x4*)&xh[o] = h;  *(u16x4*)&xm[o] = m;  *(u16x4*)&xl[o] = l;
}

// ------ transpose-convert W[K][N] f32 -> Wt[N][Kpad] bf16 (hi, optional mid/lo) ------
__global__ void transpose_w(const float* __restrict__ W, u16* __restrict__ Wh,
                            u16* __restrict__ Wm, u16* __restrict__ Wl,
                            int Kdim, int Ndim, int Kpad, long sW, long sWt) {
  __shared__ float tile[32][33];
  int e = blockIdx.z;
  int k0 = blockIdx.x * 32, n0 = blockIdx.y * 32;
  int tx = threadIdx.x, ty = threadIdx.y;       // (32,8)
  const float* Wb = W + (long)e * sW;
  #pragma unroll
  for (int i = 0; i < 4; ++i) {
    int k = k0 + ty + i * 8;
    tile[ty + i * 8][tx] = (k < Kdim) ? Wb[(long)k * Ndim + (n0 + tx)] : 0.f;
  }
  __syncthreads();
  #pragma unroll
  for (int i = 0; i < 4; ++i) {
    int n = n0 + ty + i * 8;
    float v = tile[tx][ty + i * 8];
    long o = (long)e * sWt + (long)n * Kpad + k0 + tx;
    u16 hi = f2bf(v);
    Wh[o] = hi;
    if (Wm) {
      float r1 = v - bf2f(hi);
      u16 mi = f2bf(r1);
      Wm[o] = mi;
      Wl[o] = f2bf(r1 - bf2f(mi));
    }
  }
}

// ------- Router GEMM, 3-plane bf16 emulated f32, FUSED logits partials -------
// 1-D grid 128*8, XCD-swizzled: all 8 n-tiles of an m-tile on one XCD (A-tile L2 reuse).
__global__ __launch_bounds__(256, 2)
void router_gemm_emul3(const u16* __restrict__ Ah, const u16* __restrict__ Am, const u16* __restrict__ Al,
                       const u16* __restrict__ Bh, const u16* __restrict__ Bm, const u16* __restrict__ Bl,
                       const float* __restrict__ bias, const float* __restrict__ Rw2,
                       float* __restrict__ pbuf) {
  __shared__ __align__(16) u16 S[6][128 * 32];   // 0..2 = A planes, 3..5 = B planes
  int tid = threadIdx.x;
  int bid = blockIdx.x;
  int xcd = bid & 7, j = bid >> 3;
  int mt = (j >> 3) * 8 + xcd, nt = j & 7;
  int m0 = mt * 128, n0 = nt * 128;
  const u16* Ap[3] = {Ah, Am, Al};
  const u16* Bp[3] = {Bh, Bm, Bl};
  const u16 *ag[3][2], *bg[3][2];
  u16 *la[3][2], *lb[3][2];
  #pragma unroll
  for (int r = 0; r < 2; ++r) {
    int i = r * 256 + tid;
    int row = i >> 2;
    int qa = (i & 3) ^ ((row >> 1) & 3);        // swizzled quad for this slot
    int kq = qa * 8;
    #pragma unroll
    for (int p = 0; p < 3; ++p) {
      ag[p][r] = Ap[p] + (long)(m0 + row) * KP1 + kq;
      bg[p][r] = Bp[p] + (long)(n0 + row) * KP1 + kq;
      la[p][r] = &S[p][i * 8];
      lb[p][r] = &S[3 + p][i * 8];
    }
  }
  int lane = tid & 63, wv = tid >> 6;
  int wm = wv >> 1, wn = wv & 1;
  int q = lane >> 4, c = lane & 15;
  int offA[4], offB[4];
  #pragma unroll
  for (int t4 = 0; t4 < 4; ++t4) {
    offA[t4] = swz_u16(wm * 64 + t4 * 16 + c, q);
    offB[t4] = swz_u16(wn * 64 + t4 * 16 + c, q);
  }
  f32x4 acc[4][4];
  #pragma unroll
  for (int mi = 0; mi < 4; ++mi)
    #pragma unroll
    for (int ni = 0; ni < 4; ++ni) acc[mi][ni] = (f32x4){0.f, 0.f, 0.f, 0.f};

  for (int k0 = 0; k0 < KP1; k0 += 32) {
    __syncthreads();
    #pragma unroll
    for (int r = 0; r < 2; ++r)
      #pragma unroll
      for (int p = 0; p < 3; ++p) {
        GLDS16(ag[p][r] + k0, la[p][r]);
        GLDS16(bg[p][r] + k0, lb[p][r]);
      }
    __syncthreads();
    bf16x8 av[3][4], bv[3][4];
    #pragma unroll
    for (int mi = 0; mi < 4; ++mi)
      #pragma unroll
      for (int p = 0; p < 3; ++p) av[p][mi] = *(const bf16x8*)&S[p][offA[mi]];
    #pragma unroll
    for (int ni = 0; ni < 4; ++ni)
      #pragma unroll
      for (int p = 0; p < 3; ++p) bv[p][ni] = *(const bf16x8*)&S[3 + p][offB[ni]];
    #pragma unroll
    for (int mi = 0; mi < 4; ++mi)
      #pragma unroll
      for (int ni = 0; ni < 4; ++ni) {
        acc[mi][ni] = __builtin_amdgcn_mfma_f32_16x16x32_bf16(av[0][mi], bv[0][ni], acc[mi][ni], 0, 0, 0);
        acc[mi][ni] = __builtin_amdgcn_mfma_f32_16x16x32_bf16(av[0][mi], bv[1][ni], acc[mi][ni], 0, 0, 0);
        acc[mi][ni] = __builtin_amdgcn_mfma_f32_16x16x32_bf16(av[1][mi], bv[0][ni], acc[mi][ni], 0, 0, 0);
        acc[mi][ni] = __builtin_amdgcn_mfma_f32_16x16x32_bf16(av[0][mi], bv[2][ni], acc[mi][ni], 0, 0, 0);
        acc[mi][ni] = __builtin_amdgcn_mfma_f32_16x16x32_bf16(av[2][mi], bv[0][ni], acc[mi][ni], 0, 0, 0);
      }
  }
  // ---- fused epilogue: partial logits for this 64-col half ----
  float rw2f[4][8];
  #pragma unroll
  for (int ni = 0; ni < 4; ++ni) {
    const float* p = Rw2 + (long)(n0 + wn * 64 + ni * 16 + c) * NE;
    f32x4 a = *(const f32x4*)p, b2 = *(const f32x4*)(p + 4);
    #pragma unroll
    for (int j2 = 0; j2 < 4; ++j2) { rw2f[ni][j2] = a[j2]; rw2f[ni][4 + j2] = b2[j2]; }
  }
  float bi[4];
  #pragma unroll
  for (int ni = 0; ni < 4; ++ni) bi[ni] = bias[n0 + wn * 64 + ni * 16 + c];
  #pragma unroll
  for (int mi = 0; mi < 4; ++mi)
    #pragma unroll
    for (int r = 0; r < 4; ++r) {
      int token = m0 + wm * 64 + mi * 16 + q * 4 + r;
      float part[8] = {0.f, 0.f, 0.f, 0.f, 0.f, 0.f, 0.f, 0.f};
      #pragma unroll
      for (int ni = 0; ni < 4; ++ni) {
        float v = acc[mi][ni][r] + bi[ni];
        v = v / (1.f + expf(-v));               // high-precision silu
        #pragma unroll
        for (int e = 0; e < 8; ++e) part[e] += v * rw2f[ni][e];
      }
      #pragma unroll
      for (int m = 1; m < 16; m <<= 1)          // butterfly over c (lane&15)
        #pragma unroll
        for (int e = 0; e < 8; ++e) part[e] += __shfl_xor(part[e], m, 64);
      if (c == 0) {
        float* dst = pbuf + ((long)(nt * 2 + wn) * NB + token) * 8;
        *(f32x4*)dst       = (f32x4){part[0], part[1], part[2], part[3]};
        *(f32x4*)(dst + 4) = (f32x4){part[4], part[5], part[6], part[7]};
      }
    }
}

// ---- reduce 16 half-plane partials -> logits -> top-2 -> softmax -> counts ----
__global__ void reduce_topk(const float* __restrict__ pbuf, const float* __restrict__ Rb2,
                            int* __restrict__ tk_idx, float* __restrict__ tk_alpha,
                            int* __restrict__ ctrl) {
  __shared__ int lh[NE];
  int tid = threadIdx.x;
  if (tid < NE) lh[tid] = 0;
  __syncthreads();
  int token = blockIdx.x * 256 + tid;             // grid = NB/256
  float v[8];
  #pragma unroll
  for (int e = 0; e < 8; ++e) v[e] = Rb2[e];
  #pragma unroll
  for (int p = 0; p < 16; ++p) {
    const float* src = pbuf + ((long)p * NB + token) * 8;
    f32x4 a = *(const f32x4*)src, b = *(const f32x4*)(src + 4);
    #pragma unroll
    for (int j = 0; j < 4; ++j) { v[j] += a[j]; v[4 + j] += b[j]; }
  }
  int i0 = 0;
  #pragma unroll
  for (int e = 1; e < NE; ++e) if (v[e] > v[i0]) i0 = e;     // strict: lowest idx on tie
  int i1 = -1;
  #pragma unroll
  for (int e = 0; e < NE; ++e) { if (e == i0) continue; if (i1 < 0 || v[e] > v[i1]) i1 = e; }
  float d  = v[i1] - v[i0];
  float e1 = expf(d);
  float a0 = 1.f / (1.f + e1);
  float a1 = e1 / (1.f + e1);
  tk_idx[token * 2]     = i0;  tk_idx[token * 2 + 1]   = i1;
  tk_alpha[token * 2]   = a0;  tk_alpha[token * 2 + 1] = a1;
  atomicAdd(&lh[i0], 1);  atomicAdd(&lh[i1], 1);
  __syncthreads();
  if (tid < NE) atomicAdd(&ctrl[tid * 16], lh[tid]);   // counts, 64B-padded lines
}

__global__ void compute_offsets(int* __restrict__ ctrl) {
  if (threadIdx.x == 0 && blockIdx.x == 0) {
    int total = 0;
    for (int e = 0; e < NE; ++e) {
      ctrl[256 + e] = total;
      total += (ctrl[e * 16] + 127) & ~127;       // pad each expert segment to 128 rows
    }
    ctrl[256 + NE] = total;
  }
}

// ------- block-aggregated rowmap: LDS rank + ONE global atomic per (expert,block) -------
__global__ void build_rowmap(const int* __restrict__ tk_idx, int* __restrict__ ctrl,
                             int* __restrict__ grow, int* __restrict__ tok2slot) {
  __shared__ int lh[NE];
  __shared__ int gb[NE];
  int tid = threadIdx.x;
  if (tid < NE) lh[tid] = 0;
  __syncthreads();
  int token = blockIdx.x * 256 + tid;             // grid = NB/256
  int e0 = tk_idx[token * 2], e1 = tk_idx[token * 2 + 1];
  int l0 = atomicAdd(&lh[e0], 1);
  int l1 = atomicAdd(&lh[e1], 1);
  __syncthreads();
  if (tid < NE) gb[tid] = atomicAdd(&ctrl[128 + tid * 16], lh[tid]);  // cursor, padded
  __syncthreads();
  int g0 = ctrl[256 + e0] + gb[e0] + l0;
  int g1 = ctrl[256 + e1] + gb[e1] + l1;
  grow[g0] = token;  grow[g1] = token;
  tok2slot[token * 2] = g0;  tok2slot[token * 2 + 1] = g1;
}

// -------- Grouped expert GEMM: 128x128 tile, BK = 32*NKT, swizzled LDS, XCD-swizzled grid --------
// 1-D grid GMT*NT; all NT n-tiles of one m-tile land on one XCD (A-tile fetched once).
template<int NKT, int NT, bool GATHER, bool SILU, bool OUTF32>
__global__ __launch_bounds__(256, 2)
void gemm_grouped(const u16* __restrict__ A, int lda,
                  const u16* __restrict__ Wt, long wstride, int ldw,
                  const float* __restrict__ bias, int bstride,
                  u16* __restrict__ C, int ldc,
                  float* __restrict__ Out, int ldo,
                  const int* __restrict__ offp,
                  const int* __restrict__ grow,
                  int K) {
  int bid = blockIdx.x;
  int xcd = bid & 7, j = bid >> 3;
  int mt = (j / NT) * 8 + xcd, nt = j % NT;       // NT is 2 or 8: folds to shifts
  int m0 = mt * 128, n0 = nt * 128;
  if (m0 >= offp[NE]) return;                     // block-uniform early out
  int e = 0;
  while (m0 >= offp[e + 1]) ++e;
  __shared__ __align__(16) u16 As[NKT][128 * 32];
  __shared__ __align__(16) u16 Bs[NKT][128 * 32];
  int tid = threadIdx.x;
  const u16 *ag[NKT][2], *bg[NKT][2];
  u16 *la[NKT][2], *lb[NKT][2];
  #pragma unroll
  for (int s = 0; s < NKT; ++s)
    #pragma unroll
    for (int r = 0; r < 2; ++r) {
      int i = r * 256 + tid;
      int row = i >> 2;
      int qa = (i & 3) ^ ((row >> 1) & 3);        // swizzled quad for this slot
      int kq = qa * 8 + s * 32;
      long arow = m0 + row;
      if (GATHER) arow = grow[arow];
      ag[s][r] = A + arow * lda + kq;
      bg[s][r] = Wt + (long)e * wstride + (long)(n0 + row) * ldw + kq;
      la[s][r] = &As[s][i * 8];
      lb[s][r] = &Bs[s][i * 8];
    }
  int lane = tid & 63, wv = tid >> 6;
  int wm = wv >> 1, wn = wv & 1;
  int q = lane >> 4, c = lane & 15;
  int offA[4], offB[4];
  #pragma unroll
  for (int t4 = 0; t4 < 4; ++t4) {
    offA[t4] = swz_u16(wm * 64 + t4 * 16 + c, q);
    offB[t4] = swz_u16(wn * 64 + t4 * 16 + c, q);
  }
  f32x4 acc[4][4];
  #pragma unroll
  for (int mi = 0; mi < 4; ++mi)
    #pragma unroll
    for (int ni = 0; ni < 4; ++ni) acc[mi][ni] = (f32x4){0.f, 0.f, 0.f, 0.f};

  for (int k0 = 0; k0 < K; k0 += 32 * NKT) {
    __syncthreads();
    #pragma unroll
    for (int s = 0; s < NKT; ++s)
      #pragma unroll
      for (int r = 0; r < 2; ++r) {
        GLDS16(ag[s][r] + k0, la[s][r]);
        GLDS16(bg[s][r] + k0, lb[s][r]);
      }
    __syncthreads();
    #pragma unroll
    for (int s = 0; s < NKT; ++s) {
      bf16x8 av[4], bv[4];
      #pragma unroll
      for (int mi = 0; mi < 4; ++mi)
        av[mi] = *(const bf16x8*)&As[s][offA[mi]];
      #pragma unroll
      for (int ni = 0; ni < 4; ++ni)
        bv[ni] = *(const bf16x8*)&Bs[s][offB[ni]];
      #pragma unroll
      for (int mi = 0; mi < 4; ++mi)
        #pragma unroll
        for (int ni = 0; ni < 4; ++ni)
          acc[mi][ni] = __builtin_amdgcn_mfma_f32_16x16x32_bf16(av[mi], bv[ni], acc[mi][ni], 0, 0, 0);
    }
  }
  #pragma unroll
  for (int mi = 0; mi < 4; ++mi)
    #pragma unroll
    for (int r = 0; r < 4; ++r) {
      int row = wm * 64 + mi * 16 + q * 4 + r;
      #pragma unroll
      for (int ni = 0; ni < 4; ++ni) {
        int col = n0 + wn * 64 + ni * 16 + c;
        float v = acc[mi][ni][r] + bias[e * bstride + col];
        if constexpr (SILU) v = v / (1.f + __expf(-v));
        if constexpr (OUTF32) {
          Out[(long)(m0 + row) * ldo + col] = v;
        } else {
          C[(long)(m0 + row) * ldc + col] = f2bf(v);
        }
      }
    }
}

// ---------------- combine: out[token] = a0*eo[slot0] + a1*eo[slot1] ----------------
__global__ void combine_out(const float* __restrict__ eo, const int* __restrict__ tok2slot,
                            const float* __restrict__ tk_alpha, float* __restrict__ out) {
  int i = blockIdx.x * 256 + threadIdx.x;         // grid exact: NB*DD/4/256
  int token = i >> 6, c4 = (i & 63) * 4;
  long s0 = tok2slot[token * 2], s1 = tok2slot[token * 2 + 1];
  float a0 = tk_alpha[token * 2], a1 = tk_alpha[token * 2 + 1];
  f32x4 v0 = *(const f32x4*)&eo[s0 * DD + c4];
  f32x4 v1 = *(const f32x4*)&eo[s1 * DD + c4];
  f32x4 r;
  #pragma unroll
  for (int j = 0; j < 4; ++j) r[j] = a0 * v0[j] + a1 * v1[j];
  *(f32x4*)&out[(long)token * DD + c4] = r;
}

extern "C" void kernel_launch(void* const* d_in, const int* in_sizes, int n_in,
                              void* d_out, int out_size, void* d_ws, size_t ws_size,
                              hipStream_t stream) {
  const float* t   = (const float*)d_in[0];
  const float* x   = (const float*)d_in[1];
  const float* Rw1 = (const float*)d_in[2];
  const float* Rb1 = (const float*)d_in[3];
  const float* Rw2 = (const float*)d_in[4];
  const float* Rb2 = (const float*)d_in[5];
  const float* Eb1 = (const float*)d_in[7];
  const float* Ew1 = (const float*)d_in[6];
  const float* Ew2 = (const float*)d_in[8];
  const float* Eb2 = (const float*)d_in[9];
  const float* Ew3 = (const float*)d_in[10];
  const float* Eb3 = (const float*)d_in[11];
  float* out = (float*)d_out;                     // reference output dtype is float32

  char* w = (char*)d_ws;
  size_t off = 0;
  auto alloc = [&](size_t bytes) { char* p = w + off; off = (off + bytes + 255) & ~(size_t)255; return p; };
  int*   ctrl     = (int*)  alloc(CTRL_INTS * 4);
  int*   grow     = (int*)  alloc((size_t)GMAX * 4);
  size_t zero_end = off;                                       // ctrl + grow need zeroing
  int*   tok2slot = (int*)  alloc((size_t)NB * 2 * 4);
  int*   tk_idx   = (int*)  alloc((size_t)NB * 2 * 4);
  float* tk_alpha = (float*)alloc((size_t)NB * 2 * 4);
  float* pbuf     = (float*)alloc((size_t)16 * NB * 8 * 4);    // 16 half-plane logits partials
  u16* xh  = (u16*)alloc((size_t)NB * KP1 * 2);
  u16* xm  = (u16*)alloc((size_t)NB * KP1 * 2);
  u16* xl  = (u16*)alloc((size_t)NB * KP1 * 2);
  u16* R1h = (u16*)alloc((size_t)HH * KP1 * 2);
  u16* R1m = (u16*)alloc((size_t)HH * KP1 * 2);
  u16* R1l = (u16*)alloc((size_t)HH * KP1 * 2);
  u16* E1t = (u16*)alloc((size_t)NE * HH * KP1 * 2);
  u16* E2t = (u16*)alloc((size_t)NE * HH * HH * 2);
  u16* E3t = (u16*)alloc((size_t)NE * DD * HH * 2);
  u16* H1  = (u16*)alloc((size_t)GMAX * HH * 2);
  u16* H2  = (u16*)alloc((size_t)GMAX * HH * 2);
  float* eo = (float*)H1;    // GMAX*DD*4 = 35MB <= 69MB; written by G3 after G2 consumed H1

  hipMemsetAsync(d_ws, 0, zero_end, stream);       // counts/cursor/offp + grow (pad rows -> token 0)

  build_xt3<<<(NB * 72) / 256, 256, 0, stream>>>(x, t, xh, xm, xl);
  dim3 tb(32, 8);
  transpose_w<<<dim3(KP1 / 32, HH / 32, 1),  tb, 0, stream>>>(Rw1, R1h, R1m, R1l, DIN, HH, KP1, 0, 0);
  transpose_w<<<dim3(KP1 / 32, HH / 32, NE), tb, 0, stream>>>(Ew1, E1t, nullptr, nullptr, DIN, HH, KP1, (long)DIN * HH, (long)HH * KP1);
  transpose_w<<<dim3(HH / 32, HH / 32, NE),  tb, 0, stream>>>(Ew2, E2t, nullptr, nullptr, HH, HH, HH, (long)HH * HH, (long)HH * HH);
  transpose_w<<<dim3(HH / 32, DD / 32, NE),  tb, 0, stream>>>(Ew3, E3t, nullptr, nullptr, HH, DD, HH, (long)HH * DD, (long)DD * HH);

  router_gemm_emul3<<<(NB / 128) * 8, 256, 0, stream>>>(xh, xm, xl, R1h, R1m, R1l, Rb1, Rw2, pbuf);
  reduce_topk<<<NB / 256, 256, 0, stream>>>(pbuf, Rb2, tk_idx, tk_alpha, ctrl);
  compute_offsets<<<1, 64, 0, stream>>>(ctrl);
  build_rowmap<<<NB / 256, 256, 0, stream>>>(tk_idx, ctrl, grow, tok2slot);

  const int* offp = ctrl + 256;
  // G1: H1 = silu(gather(xt_hi) @ Ew1^T + Eb1)   (K=288 -> NKT=3, BK=96, 3 iters)
  gemm_grouped<3, 8, true, true, false><<<GMT * 8, 256, 0, stream>>>(
      xh, KP1, E1t, (long)HH * KP1, KP1, Eb1, HH, H1, HH, nullptr, 0, offp, grow, KP1);
  // G2: H2 = silu(H1 @ Ew2^T + Eb2)              (K=1024 -> NKT=2, BK=64)
  gemm_grouped<2, 8, false, true, false><<<GMT * 8, 256, 0, stream>>>(
      H1, HH, E2t, (long)HH * HH, HH, Eb2, HH, H2, HH, nullptr, 0, offp, nullptr, HH);
  // G3: eo[slot] = H2 @ Ew3^T + Eb3              (K=1024 -> NKT=2, NT=2)
  gemm_grouped<2, 2, false, false, true><<<GMT * 2, 256, 0, stream>>>(
      H2, HH, E3t, (long)DD * HH, HH, Eb3, DD, nullptr, 0, eo, DD, offp, nullptr, HH);
  // out[token] = a0*eo[s0] + a1*eo[s1]
  combine_out<<<(NB * DD / 4) / 256, 256, 0, stream>>>(eo, tok2slot, tk_alpha, out);
}

// Round 8
// 398.602 us; speedup vs baseline: 1.1024x; 1.0229x over previous
//
#include <hip/hip_runtime.h>
#include <cstdint>
#include <cstddef>

// Problem dims
#define NB   16384   // batch tokens
#define DD   256     // model dim
#define DIN  257     // D+1 (x ++ t)
#define KP1  288     // DIN padded to mult of 32
#define HH   1024    // hidden
#define NE   8       // experts
#define GMAX 33792   // 264*128: 2*NB rows + per-expert pad to 128
#define GMT  264     // GMAX/128 row tiles (divisible by 8)

// ctrl layout (ints), atomics padded to separate 64B lines:
//   counts[e] at ctrl[e*16]; cursor[e] at ctrl[128+e*16]; offp[e] at ctrl[256+e] (offp[8]=total)
//   done-counter at ctrl[270]
#define CTRL_INTS 272

typedef unsigned short u16;
typedef __bf16 bf16x8 __attribute__((ext_vector_type(8)));
typedef float  f32x4  __attribute__((ext_vector_type(4)));
typedef unsigned short u16x4 __attribute__((ext_vector_type(4)));

__device__ __forceinline__ u16 f2bf(float f) {
  union { float f; unsigned u; } v; v.f = f;
  return (u16)((v.u + 0x7FFFu + ((v.u >> 16) & 1u)) >> 16);  // RNE
}
__device__ __forceinline__ float bf2f(u16 h) {
  union { unsigned u; float f; } v; v.u = ((unsigned)h) << 16;
  return v.f;
}

#define GLDS16(g, l) __builtin_amdgcn_global_load_lds( \
    (const __attribute__((address_space(1))) void*)(g), \
    (__attribute__((address_space(3))) void*)(l), 16, 0, 0)

// LDS k-quad swizzle: quad q of tile-row r lives at slot r*4 + (q ^ ((r>>1)&3)).
// Write side stays lane-contiguous (global_load_lds constraint); read side gets
// distinct bank-sets within each 8-lane phase of ds_read_b128 (conflicts: 8.5M -> 0).
__device__ __forceinline__ int swz_u16(int row, int q) {
  return row * 32 + ((q ^ ((row >> 1) & 3)) * 8);
}

// ---------------- xt = [x, t, 0-pad] as 3 bf16 planes, vectorized x4 ----------------
__global__ void build_xt3(const float* __restrict__ x, const float* __restrict__ t,
                          u16* __restrict__ xh, u16* __restrict__ xm, u16* __restrict__ xl) {
  long i = (long)blockIdx.x * 256 + threadIdx.x;   // grid exact: NB*72/256
  int b = (int)(i / 72), qd = (int)(i % 72);       // 72 quads of 4 = KP1
  f32x4 v;
  if (qd < 64)       v = *(const f32x4*)&x[(long)b * DD + qd * 4];
  else if (qd == 64) v = (f32x4){t[b], 0.f, 0.f, 0.f};
  else               v = (f32x4){0.f, 0.f, 0.f, 0.f};
  u16x4 h, m, l;
  #pragma unroll
  for (int j = 0; j < 4; ++j) {
    u16 hi = f2bf(v[j]);  float r1 = v[j] - bf2f(hi);
    u16 mi = f2bf(r1);    float r2 = r1 - bf2f(mi);
    h[j] = hi; m[j] = mi; l[j] = f2bf(r2);
  }
  long o = (long)b * KP1 + qd * 4;
  *(u16x4*)&xh[o] = h;  *(u16x4*)&xm[o] = m;  *(u16x4*)&xl[o] = l;
}

// ------ ALL weight transposes in one launch: W[K][N] f32 -> Wt[N][Kpad] bf16 ------
// Flat grid decode: seg0 Rw1(3-plane) 288 | seg1 Ew1 2304 | seg2 Ew2 8192 | seg3 Ew3 2048
__global__ void transpose_all(const float* __restrict__ Rw1, const float* __restrict__ Ew1,
                              const float* __restrict__ Ew2, const float* __restrict__ Ew3,
                              u16* __restrict__ R1h, u16* __restrict__ R1m, u16* __restrict__ R1l,
                              u16* __restrict__ E1t, u16* __restrict__ E2t, u16* __restrict__ E3t) {
  __shared__ float tile[32][33];
  int bid = blockIdx.x;
  const float* W; u16 *Wh, *Wm = nullptr, *Wl = nullptr;
  int Kdim, Ndim, Kpad, e = 0, kt, nt;
  long sW = 0, sWt = 0;
  if (bid < 288) {                                  // Rw1: 9 k-tiles x 32 n-tiles
    kt = bid % 9; nt = bid / 9;
    W = Rw1; Wh = R1h; Wm = R1m; Wl = R1l; Kdim = DIN; Ndim = HH; Kpad = KP1;
  } else if (bid < 2592) {                          // Ew1: 8 x (9 x 32)
    int b = bid - 288; e = b / 288; b %= 288; kt = b % 9; nt = b / 9;
    W = Ew1; Wh = E1t; Kdim = DIN; Ndim = HH; Kpad = KP1; sW = (long)DIN * HH; sWt = (long)HH * KP1;
  } else if (bid < 10784) {                         // Ew2: 8 x (32 x 32)
    int b = bid - 2592; e = b / 1024; b %= 1024; kt = b % 32; nt = b / 32;
    W = Ew2; Wh = E2t; Kdim = HH; Ndim = HH; Kpad = HH; sW = (long)HH * HH; sWt = (long)HH * HH;
  } else {                                          // Ew3: 8 x (32 x 8)
    int b = bid - 10784; e = b / 256; b %= 256; kt = b % 32; nt = b / 32;
    W = Ew3; Wh = E3t; Kdim = HH; Ndim = DD; Kpad = HH; sW = (long)HH * DD; sWt = (long)DD * HH;
  }
  int k0 = kt * 32, n0 = nt * 32;
  int tx = threadIdx.x, ty = threadIdx.y;           // (32,8)
  const float* Wb = W + (long)e * sW;
  #pragma unroll
  for (int i = 0; i < 4; ++i) {
    int k = k0 + ty + i * 8;
    tile[ty + i * 8][tx] = (k < Kdim) ? Wb[(long)k * Ndim + (n0 + tx)] : 0.f;
  }
  __syncthreads();
  #pragma unroll
  for (int i = 0; i < 4; ++i) {
    int n = n0 + ty + i * 8;
    float v = tile[tx][ty + i * 8];
    long o = (long)e * sWt + (long)n * Kpad + k0 + tx;
    u16 hi = f2bf(v);
    Wh[o] = hi;
    if (Wm) {
      float r1 = v - bf2f(hi);
      u16 mi = f2bf(r1);
      Wm[o] = mi;
      Wl[o] = f2bf(r1 - bf2f(mi));
    }
  }
}

// ------- Router GEMM, 3-plane bf16 emulated f32, FUSED logits partials -------
// 1-D grid 128*8, XCD-swizzled: all 8 n-tiles of an m-tile on one XCD (A-tile L2 reuse).
__global__ __launch_bounds__(256, 2)
void router_gemm_emul3(const u16* __restrict__ Ah, const u16* __restrict__ Am, const u16* __restrict__ Al,
                       const u16* __restrict__ Bh, const u16* __restrict__ Bm, const u16* __restrict__ Bl,
                       const float* __restrict__ bias, const float* __restrict__ Rw2,
                       float* __restrict__ pbuf) {
  __shared__ __align__(16) u16 S[6][128 * 32];   // 0..2 = A planes, 3..5 = B planes
  int tid = threadIdx.x;
  int bid = blockIdx.x;
  int xcd = bid & 7, j = bid >> 3;
  int mt = (j >> 3) * 8 + xcd, nt = j & 7;
  int m0 = mt * 128, n0 = nt * 128;
  const u16* Ap[3] = {Ah, Am, Al};
  const u16* Bp[3] = {Bh, Bm, Bl};
  const u16 *ag[3][2], *bg[3][2];
  u16 *la[3][2], *lb[3][2];
  #pragma unroll
  for (int r = 0; r < 2; ++r) {
    int i = r * 256 + tid;
    int row = i >> 2;
    int qa = (i & 3) ^ ((row >> 1) & 3);        // swizzled quad for this slot
    int kq = qa * 8;
    #pragma unroll
    for (int p = 0; p < 3; ++p) {
      ag[p][r] = Ap[p] + (long)(m0 + row) * KP1 + kq;
      bg[p][r] = Bp[p] + (long)(n0 + row) * KP1 + kq;
      la[p][r] = &S[p][i * 8];
      lb[p][r] = &S[3 + p][i * 8];
    }
  }
  int lane = tid & 63, wv = tid >> 6;
  int wm = wv >> 1, wn = wv & 1;
  int q = lane >> 4, c = lane & 15;
  int offA[4], offB[4];
  #pragma unroll
  for (int t4 = 0; t4 < 4; ++t4) {
    offA[t4] = swz_u16(wm * 64 + t4 * 16 + c, q);
    offB[t4] = swz_u16(wn * 64 + t4 * 16 + c, q);
  }
  f32x4 acc[4][4];
  #pragma unroll
  for (int mi = 0; mi < 4; ++mi)
    #pragma unroll
    for (int ni = 0; ni < 4; ++ni) acc[mi][ni] = (f32x4){0.f, 0.f, 0.f, 0.f};

  for (int k0 = 0; k0 < KP1; k0 += 32) {
    __syncthreads();
    #pragma unroll
    for (int r = 0; r < 2; ++r)
      #pragma unroll
      for (int p = 0; p < 3; ++p) {
        GLDS16(ag[p][r] + k0, la[p][r]);
        GLDS16(bg[p][r] + k0, lb[p][r]);
      }
    __syncthreads();
    bf16x8 av[3][4], bv[3][4];
    #pragma unroll
    for (int mi = 0; mi < 4; ++mi)
      #pragma unroll
      for (int p = 0; p < 3; ++p) av[p][mi] = *(const bf16x8*)&S[p][offA[mi]];
    #pragma unroll
    for (int ni = 0; ni < 4; ++ni)
      #pragma unroll
      for (int p = 0; p < 3; ++p) bv[p][ni] = *(const bf16x8*)&S[3 + p][offB[ni]];
    #pragma unroll
    for (int mi = 0; mi < 4; ++mi)
      #pragma unroll
      for (int ni = 0; ni < 4; ++ni) {
        acc[mi][ni] = __builtin_amdgcn_mfma_f32_16x16x32_bf16(av[0][mi], bv[0][ni], acc[mi][ni], 0, 0, 0);
        acc[mi][ni] = __builtin_amdgcn_mfma_f32_16x16x32_bf16(av[0][mi], bv[1][ni], acc[mi][ni], 0, 0, 0);
        acc[mi][ni] = __builtin_amdgcn_mfma_f32_16x16x32_bf16(av[1][mi], bv[0][ni], acc[mi][ni], 0, 0, 0);
        acc[mi][ni] = __builtin_amdgcn_mfma_f32_16x16x32_bf16(av[0][mi], bv[2][ni], acc[mi][ni], 0, 0, 0);
        acc[mi][ni] = __builtin_amdgcn_mfma_f32_16x16x32_bf16(av[2][mi], bv[0][ni], acc[mi][ni], 0, 0, 0);
      }
  }
  // ---- fused epilogue: partial logits for this 64-col half ----
  float rw2f[4][8];
  #pragma unroll
  for (int ni = 0; ni < 4; ++ni) {
    const float* p = Rw2 + (long)(n0 + wn * 64 + ni * 16 + c) * NE;
    f32x4 a = *(const f32x4*)p, b2 = *(const f32x4*)(p + 4);
    #pragma unroll
    for (int j2 = 0; j2 < 4; ++j2) { rw2f[ni][j2] = a[j2]; rw2f[ni][4 + j2] = b2[j2]; }
  }
  float bi[4];
  #pragma unroll
  for (int ni = 0; ni < 4; ++ni) bi[ni] = bias[n0 + wn * 64 + ni * 16 + c];
  #pragma unroll
  for (int mi = 0; mi < 4; ++mi)
    #pragma unroll
    for (int r = 0; r < 4; ++r) {
      int token = m0 + wm * 64 + mi * 16 + q * 4 + r;
      float part[8] = {0.f, 0.f, 0.f, 0.f, 0.f, 0.f, 0.f, 0.f};
      #pragma unroll
      for (int ni = 0; ni < 4; ++ni) {
        float v = acc[mi][ni][r] + bi[ni];
        v = v / (1.f + expf(-v));               // high-precision silu
        #pragma unroll
        for (int e = 0; e < 8; ++e) part[e] += v * rw2f[ni][e];
      }
      #pragma unroll
      for (int m = 1; m < 16; m <<= 1)          // butterfly over c (lane&15)
        #pragma unroll
        for (int e = 0; e < 8; ++e) part[e] += __shfl_xor(part[e], m, 64);
      if (c == 0) {
        float* dst = pbuf + ((long)(nt * 2 + wn) * NB + token) * 8;
        *(f32x4*)dst       = (f32x4){part[0], part[1], part[2], part[3]};
        *(f32x4*)(dst + 4) = (f32x4){part[4], part[5], part[6], part[7]};
      }
    }
}

// ---- reduce 16 half-plane partials -> logits -> top-2 -> softmax -> counts ----
// Last block also computes the padded segment offsets (device-scope atomic handshake).
__global__ void reduce_topk(const float* __restrict__ pbuf, const float* __restrict__ Rb2,
                            int* __restrict__ tk_idx, float* __restrict__ tk_alpha,
                            int* __restrict__ ctrl) {
  __shared__ int lh[NE];
  int tid = threadIdx.x;
  if (tid < NE) lh[tid] = 0;
  __syncthreads();
  int token = blockIdx.x * 256 + tid;             // grid = NB/256
  float v[8];
  #pragma unroll
  for (int e = 0; e < 8; ++e) v[e] = Rb2[e];
  #pragma unroll
  for (int p = 0; p < 16; ++p) {
    const float* src = pbuf + ((long)p * NB + token) * 8;
    f32x4 a = *(const f32x4*)src, b = *(const f32x4*)(src + 4);
    #pragma unroll
    for (int j = 0; j < 4; ++j) { v[j] += a[j]; v[4 + j] += b[j]; }
  }
  int i0 = 0;
  #pragma unroll
  for (int e = 1; e < NE; ++e) if (v[e] > v[i0]) i0 = e;     // strict: lowest idx on tie
  int i1 = -1;
  #pragma unroll
  for (int e = 0; e < NE; ++e) { if (e == i0) continue; if (i1 < 0 || v[e] > v[i1]) i1 = e; }
  float d  = v[i1] - v[i0];
  float e1 = expf(d);
  float a0 = 1.f / (1.f + e1);
  float a1 = e1 / (1.f + e1);
  tk_idx[token * 2]     = i0;  tk_idx[token * 2 + 1]   = i1;
  tk_alpha[token * 2]   = a0;  tk_alpha[token * 2 + 1] = a1;
  atomicAdd(&lh[i0], 1);  atomicAdd(&lh[i1], 1);
  __syncthreads();
  if (tid < NE) atomicAdd(&ctrl[tid * 16], lh[tid]);   // counts, 64B-padded lines
  __syncthreads();
  if (tid == 0) {
    __threadfence();
    int done = atomicAdd(&ctrl[270], 1);
    if (done == gridDim.x - 1) {                       // last block: compute offsets
      int total = 0;
      for (int e = 0; e < NE; ++e) {
        ctrl[256 + e] = total;
        total += (atomicAdd(&ctrl[e * 16], 0) + 127) & ~127;  // pad segment to 128 rows
      }
      ctrl[256 + NE] = total;
    }
  }
}

// ------- block-aggregated rowmap: LDS rank + ONE global atomic per (expert,block) -------
__global__ void build_rowmap(const int* __restrict__ tk_idx, int* __restrict__ ctrl,
                             int* __restrict__ grow, int* __restrict__ tok2slot) {
  __shared__ int lh[NE];
  __shared__ int gb[NE];
  int tid = threadIdx.x;
  if (tid < NE) lh[tid] = 0;
  __syncthreads();
  int token = blockIdx.x * 256 + tid;             // grid = NB/256
  int e0 = tk_idx[token * 2], e1 = tk_idx[token * 2 + 1];
  int l0 = atomicAdd(&lh[e0], 1);
  int l1 = atomicAdd(&lh[e1], 1);
  __syncthreads();
  if (tid < NE) gb[tid] = atomicAdd(&ctrl[128 + tid * 16], lh[tid]);  // cursor, padded
  __syncthreads();
  int g0 = ctrl[256 + e0] + gb[e0] + l0;
  int g1 = ctrl[256 + e1] + gb[e1] + l1;
  grow[g0] = token;  grow[g1] = token;
  tok2slot[token * 2] = g0;  tok2slot[token * 2 + 1] = g1;
}

// -------- Grouped expert GEMM: 128x128 tile, BK = 32*NKT, swizzled LDS, XCD-swizzled grid --------
// 1-D grid GMT*NT; all NT n-tiles of one m-tile land on one XCD (A-tile fetched once).
// MINW: min waves/EU — raises resident blocks/CU so other blocks cover barrier drains.
template<int NKT, int NT, int MINW, bool GATHER, bool SILU, bool OUTF32>
__global__ __launch_bounds__(256, MINW)
void gemm_grouped(const u16* __restrict__ A, int lda,
                  const u16* __restrict__ Wt, long wstride, int ldw,
                  const float* __restrict__ bias, int bstride,
                  u16* __restrict__ C, int ldc,
                  float* __restrict__ Out, int ldo,
                  const int* __restrict__ offp,
                  const int* __restrict__ grow,
                  int K) {
  int bid = blockIdx.x;
  int xcd = bid & 7, j = bid >> 3;
  int mt = (j / NT) * 8 + xcd, nt = j % NT;       // NT is 2 or 8: folds to shifts
  int m0 = mt * 128, n0 = nt * 128;
  if (m0 >= offp[NE]) return;                     // block-uniform early out
  int e = 0;
  while (m0 >= offp[e + 1]) ++e;
  __shared__ __align__(16) u16 As[NKT][128 * 32];
  __shared__ __align__(16) u16 Bs[NKT][128 * 32];
  int tid = threadIdx.x;
  const u16 *ag[NKT][2], *bg[NKT][2];
  u16 *la[NKT][2], *lb[NKT][2];
  #pragma unroll
  for (int s = 0; s < NKT; ++s)
    #pragma unroll
    for (int r = 0; r < 2; ++r) {
      int i = r * 256 + tid;
      int row = i >> 2;
      int qa = (i & 3) ^ ((row >> 1) & 3);        // swizzled quad for this slot
      int kq = qa * 8 + s * 32;
      long arow = m0 + row;
      if (GATHER) arow = grow[arow];
      ag[s][r] = A + arow * lda + kq;
      bg[s][r] = Wt + (long)e * wstride + (long)(n0 + row) * ldw + kq;
      la[s][r] = &As[s][i * 8];
      lb[s][r] = &Bs[s][i * 8];
    }
  int lane = tid & 63, wv = tid >> 6;
  int wm = wv >> 1, wn = wv & 1;
  int q = lane >> 4, c = lane & 15;
  int offA[4], offB[4];
  #pragma unroll
  for (int t4 = 0; t4 < 4; ++t4) {
    offA[t4] = swz_u16(wm * 64 + t4 * 16 + c, q);
    offB[t4] = swz_u16(wn * 64 + t4 * 16 + c, q);
  }
  f32x4 acc[4][4];
  #pragma unroll
  for (int mi = 0; mi < 4; ++mi)
    #pragma unroll
    for (int ni = 0; ni < 4; ++ni) acc[mi][ni] = (f32x4){0.f, 0.f, 0.f, 0.f};

  for (int k0 = 0; k0 < K; k0 += 32 * NKT) {
    __syncthreads();
    #pragma unroll
    for (int s = 0; s < NKT; ++s)
      #pragma unroll
      for (int r = 0; r < 2; ++r) {
        GLDS16(ag[s][r] + k0, la[s][r]);
        GLDS16(bg[s][r] + k0, lb[s][r]);
      }
    __syncthreads();
    #pragma unroll
    for (int s = 0; s < NKT; ++s) {
      bf16x8 av[4], bv[4];
      #pragma unroll
      for (int mi = 0; mi < 4; ++mi)
        av[mi] = *(const bf16x8*)&As[s][offA[mi]];
      #pragma unroll
      for (int ni = 0; ni < 4; ++ni)
        bv[ni] = *(const bf16x8*)&Bs[s][offB[ni]];
      #pragma unroll
      for (int mi = 0; mi < 4; ++mi)
        #pragma unroll
        for (int ni = 0; ni < 4; ++ni)
          acc[mi][ni] = __builtin_amdgcn_mfma_f32_16x16x32_bf16(av[mi], bv[ni], acc[mi][ni], 0, 0, 0);
    }
  }
  #pragma unroll
  for (int mi = 0; mi < 4; ++mi)
    #pragma unroll
    for (int r = 0; r < 4; ++r) {
      int row = wm * 64 + mi * 16 + q * 4 + r;
      #pragma unroll
      for (int ni = 0; ni < 4; ++ni) {
        int col = n0 + wn * 64 + ni * 16 + c;
        float v = acc[mi][ni][r] + bias[e * bstride + col];
        if constexpr (SILU) v = v / (1.f + __expf(-v));
        if constexpr (OUTF32) {
          Out[(long)(m0 + row) * ldo + col] = v;
        } else {
          C[(long)(m0 + row) * ldc + col] = f2bf(v);
        }
      }
    }
}

// ---------------- combine: out[token] = a0*eo[slot0] + a1*eo[slot1] ----------------
__global__ void combine_out(const float* __restrict__ eo, const int* __restrict__ tok2slot,
                            const float* __restrict__ tk_alpha, float* __restrict__ out) {
  int i = blockIdx.x * 256 + threadIdx.x;         // grid exact: NB*DD/4/256
  int token = i >> 6, c4 = (i & 63) * 4;
  long s0 = tok2slot[token * 2], s1 = tok2slot[token * 2 + 1];
  float a0 = tk_alpha[token * 2], a1 = tk_alpha[token * 2 + 1];
  f32x4 v0 = *(const f32x4*)&eo[s0 * DD + c4];
  f32x4 v1 = *(const f32x4*)&eo[s1 * DD + c4];
  f32x4 r;
  #pragma unroll
  for (int j = 0; j < 4; ++j) r[j] = a0 * v0[j] + a1 * v1[j];
  *(f32x4*)&out[(long)token * DD + c4] = r;
}

extern "C" void kernel_launch(void* const* d_in, const int* in_sizes, int n_in,
                              void* d_out, int out_size, void* d_ws, size_t ws_size,
                              hipStream_t stream) {
  const float* t   = (const float*)d_in[0];
  const float* x   = (const float*)d_in[1];
  const float* Rw1 = (const float*)d_in[2];
  const float* Rb1 = (const float*)d_in[3];
  const float* Rw2 = (const float*)d_in[4];
  const float* Rb2 = (const float*)d_in[5];
  const float* Ew1 = (const float*)d_in[6];
  const float* Eb1 = (const float*)d_in[7];
  const float* Ew2 = (const float*)d_in[8];
  const float* Eb2 = (const float*)d_in[9];
  const float* Ew3 = (const float*)d_in[10];
  const float* Eb3 = (const float*)d_in[11];
  float* out = (float*)d_out;                     // reference output dtype is float32

  char* w = (char*)d_ws;
  size_t off = 0;
  auto alloc = [&](size_t bytes) { char* p = w + off; off = (off + bytes + 255) & ~(size_t)255; return p; };
  int*   ctrl     = (int*)  alloc(CTRL_INTS * 4);
  int*   grow     = (int*)  alloc((size_t)GMAX * 4);
  size_t zero_end = off;                                       // ctrl + grow need zeroing
  int*   tok2slot = (int*)  alloc((size_t)NB * 2 * 4);
  int*   tk_idx   = (int*)  alloc((size_t)NB * 2 * 4);
  float* tk_alpha = (float*)alloc((size_t)NB * 2 * 4);
  float* pbuf     = (float*)alloc((size_t)16 * NB * 8 * 4);    // 16 half-plane logits partials
  u16* xh  = (u16*)alloc((size_t)NB * KP1 * 2);
  u16* xm  = (u16*)alloc((size_t)NB * KP1 * 2);
  u16* xl  = (u16*)alloc((size_t)NB * KP1 * 2);
  u16* R1h = (u16*)alloc((size_t)HH * KP1 * 2);
  u16* R1m = (u16*)alloc((size_t)HH * KP1 * 2);
  u16* R1l = (u16*)alloc((size_t)HH * KP1 * 2);
  u16* E1t = (u16*)alloc((size_t)NE * HH * KP1 * 2);
  u16* E2t = (u16*)alloc((size_t)NE * HH * HH * 2);
  u16* E3t = (u16*)alloc((size_t)NE * DD * HH * 2);
  u16* H1  = (u16*)alloc((size_t)GMAX * HH * 2);
  u16* H2  = (u16*)alloc((size_t)GMAX * HH * 2);
  float* eo = (float*)H1;    // GMAX*DD*4 = 35MB <= 69MB; written by G3 after G2 consumed H1

  hipMemsetAsync(d_ws, 0, zero_end, stream);       // ctrl (incl done-counter) + grow

  build_xt3<<<(NB * 72) / 256, 256, 0, stream>>>(x, t, xh, xm, xl);
  transpose_all<<<12832, dim3(32, 8), 0, stream>>>(Rw1, Ew1, Ew2, Ew3,
                                                   R1h, R1m, R1l, E1t, E2t, E3t);

  router_gemm_emul3<<<(NB / 128) * 8, 256, 0, stream>>>(xh, xm, xl, R1h, R1m, R1l, Rb1, Rw2, pbuf);
  reduce_topk<<<NB / 256, 256, 0, stream>>>(pbuf, Rb2, tk_idx, tk_alpha, ctrl);
  build_rowmap<<<NB / 256, 256, 0, stream>>>(tk_idx, ctrl, grow, tok2slot);

  const int* offp = ctrl + 256;
  // G1: H1 = silu(gather(xt_hi) @ Ew1^T + Eb1)   (K=288 -> NKT=3, BK=96; 48KB LDS -> 3 blocks/CU)
  gemm_grouped<3, 8, 3, true, true, false><<<GMT * 8, 256, 0, stream>>>(
      xh, KP1, E1t, (long)HH * KP1, KP1, Eb1, HH, H1, HH, nullptr, 0, offp, grow, KP1);
  // G2: H2 = silu(H1 @ Ew2^T + Eb2)              (K=1024 -> NKT=2, BK=64; MINW=4 -> 4 blocks/CU)
  gemm_grouped<2, 8, 4, false, true, false><<<GMT * 8, 256, 0, stream>>>(
      H1, HH, E2t, (long)HH * HH, HH, Eb2, HH, H2, HH, nullptr, 0, offp, nullptr, HH);
  // G3: eo[slot] = H2 @ Ew3^T + Eb3              (K=1024 -> NKT=2, NT=2; MINW=4)
  gemm_grouped<2, 2, 4, false, false, true><<<GMT * 2, 256, 0, stream>>>(
      H2, HH, E3t, (long)DD * HH, HH, Eb3, DD, nullptr, 0, eo, DD, offp, nullptr, HH);
  // out[token] = a0*eo[s0] + a1*eo[s1]
  combine_out<<<(NB * DD / 4) / 256, 256, 0, stream>>>(eo, tok2slot, tk_alpha, out);
}